// Round 12
// baseline (719.165 us; speedup 1.0000x reference)
//
#include <hip/hip_runtime.h>
#include <math.h>

#define B_SZ   2
#define L_SEQ  4096
#define DIMC   128
#define DI     256      // D_INNER
#define DST    16       // D_STATE
#define DTR    8        // DT_RANK
#define NXP    40       // DTR + 2*DST
#define NXPP   48       // padded to MFMA tile
#define NLAYER 8
#define NCH    512      // chunks per batch
#define CS     8        // rows per chunk
#define LOG2E  1.4426950408889634f
#define LN2    0.6931471805599453f
#define PSA    264      // u16 LDS row stride for MFMA A tiles

#define N_INW  (NLAYER * 512 * 128)
#define N_XPW  (NLAYER * NXPP * DI)
#define N_OW   (NLAYER * DIMC * DI)
#define N_AF   (NLAYER * DI * DST)

typedef __attribute__((ext_vector_type(8))) unsigned short u16x8;
typedef __attribute__((ext_vector_type(4))) float f32x4;

__device__ __forceinline__ float fexp2(float x){ float r; asm("v_exp_f32 %0, %1" : "=v"(r) : "v"(x)); return r; }
__device__ __forceinline__ float flog2(float x){ float r; asm("v_log_f32 %0, %1" : "=v"(r) : "v"(x)); return r; }
__device__ __forceinline__ float frcp (float x){ float r; asm("v_rcp_f32 %0, %1" : "=v"(r) : "v"(x)); return r; }

__device__ __forceinline__ float silu_f(float x) {
    return x * frcp(1.f + fexp2(-x * LOG2E));
}
__device__ __forceinline__ float softplus_f(float x) {
    float t = fexp2(-fabsf(x) * LOG2E);
    return fmaxf(x, 0.f) + flog2(1.f + t) * LN2;
}
__device__ __forceinline__ void splitf(float x, unsigned short& h, unsigned short& l) {
    unsigned bx = __builtin_bit_cast(unsigned, x);
    h = (unsigned short)(bx >> 16);
    float fh = __builtin_bit_cast(float, bx & 0xffff0000u);
    float r = x - fh;
    l = (unsigned short)(__builtin_bit_cast(unsigned, r) >> 16);
}
__device__ __forceinline__ float bf2f(unsigned short u) {
    return __builtin_bit_cast(float, (unsigned)u << 16);
}

// ---------------- one prep kernel: all weight splits + Af table ----------------
__global__ void prep(const float* __restrict__ in_w, const float* __restrict__ xp_w,
                     const float* __restrict__ out_w, const float* __restrict__ A_log,
                     unsigned short* __restrict__ iwh, unsigned short* __restrict__ iwl,
                     unsigned short* __restrict__ xpwh, unsigned short* __restrict__ xpwl,
                     unsigned short* __restrict__ owh, unsigned short* __restrict__ owl,
                     float* __restrict__ Af) {
    const int i = blockIdx.x * 256 + threadIdx.x;
    if (i < N_INW) { unsigned short h, l; splitf(in_w[i], h, l); iwh[i] = h; iwl[i] = l; }
    if (i < N_XPW) {
        int ly = i / (NXPP * DI), rem = i % (NXPP * DI);
        int c = rem / DI, k = rem % DI;
        unsigned short h = 0, l = 0;
        if (c < NXP) splitf(xp_w[((size_t)ly * NXP + c) * DI + k], h, l);
        xpwh[i] = h; xpwl[i] = l;
    }
    if (i < N_OW) { unsigned short h, l; splitf(out_w[i], h, l); owh[i] = h; owl[i] = l; }
    if (i < N_AF) Af[i] = -expf(A_log[i]) * LOG2E;
}

// ---------------- transpose (B,C,L) -> (B,L,C), emit split bf16 ----------------
__global__ void transpose_in(const float* __restrict__ x, unsigned short* __restrict__ hh,
                             unsigned short* __restrict__ hl) {
    __shared__ float tl[32][33];
    const int b  = blockIdx.x;
    const int c0 = blockIdx.y * 32;
    const int l0 = blockIdx.z * 32;
    const int tx = threadIdx.x;
    const int ty = threadIdx.y;
    #pragma unroll
    for (int r = 0; r < 4; ++r) {
        int c = c0 + ty + r * 8;
        tl[ty + r * 8][tx] = x[((size_t)b * DIMC + c) * L_SEQ + l0 + tx];
    }
    __syncthreads();
    #pragma unroll
    for (int r = 0; r < 4; ++r) {
        int l = l0 + ty + r * 8;
        float v = tl[tx][ty + r * 8];
        size_t o = ((size_t)b * L_SEQ + l) * DIMC + c0 + tx;
        unsigned short h16, l16; splitf(v, h16, l16);
        hh[o] = h16; hl[o] = l16;
    }
}

// ---------------- MFMA GEMM: C[M,N] = A[M,K] * W[N,K]^T  (split-bf16, 3-pass) ----------------
template<int BM, int BN>
__global__ __launch_bounds__(256) void gemm_sp(
    const unsigned short* __restrict__ Ahg, const unsigned short* __restrict__ Alg,
    const unsigned short* __restrict__ Whg, const unsigned short* __restrict__ Wlg,
    float* __restrict__ C, int M, int N, int K) {
    constexpr int PS = 40;
    __shared__ unsigned short lds[(BM + BN) * 2 * PS];
    unsigned short* LAh = lds;
    unsigned short* LAl = LAh + BM * PS;
    unsigned short* LBh = LAl + BM * PS;
    unsigned short* LBl = LBh + BN * PS;
    const int t = threadIdx.x;
    const int w = t >> 6, l = t & 63;
    const int wr = w >> 1, wc = w & 1;
    const int lr = l & 15, lq = l >> 4;
    constexpr int MF = BM / 32, NF = BN / 32;
    const int bm = blockIdx.x * BM, bn = blockIdx.y * BN;
    f32x4 acc[MF][NF];
    const f32x4 z4 = {0.f, 0.f, 0.f, 0.f};
    #pragma unroll
    for (int m = 0; m < MF; ++m)
        #pragma unroll
        for (int n = 0; n < NF; ++n) acc[m][n] = z4;

    for (int k0 = 0; k0 < K; k0 += 32) {
        if (k0) __syncthreads();
        #pragma unroll
        for (int s = 0; s < BM * 4 / 256; ++s) {
            int task = t + s * 256;
            int r = task >> 2, g = task & 3;
            size_t go = (size_t)(bm + r) * K + k0 + g * 8;
            *(u16x8*)&LAh[r * PS + g * 8] = *(const u16x8*)&Ahg[go];
            *(u16x8*)&LAl[r * PS + g * 8] = *(const u16x8*)&Alg[go];
        }
        #pragma unroll
        for (int s = 0; s < BN * 4 / 256; ++s) {
            int task = t + s * 256;
            int r = task >> 2, g = task & 3;
            size_t go = (size_t)(bn + r) * K + k0 + g * 8;
            *(u16x8*)&LBh[r * PS + g * 8] = *(const u16x8*)&Whg[go];
            *(u16x8*)&LBl[r * PS + g * 8] = *(const u16x8*)&Wlg[go];
        }
        __syncthreads();
        u16x8 ah[MF], al[MF], bh[NF], bl[NF];
        #pragma unroll
        for (int m = 0; m < MF; ++m) {
            int rr = wr * (BM / 2) + m * 16 + lr;
            ah[m] = *(u16x8*)&LAh[rr * PS + lq * 8];
            al[m] = *(u16x8*)&LAl[rr * PS + lq * 8];
        }
        #pragma unroll
        for (int n = 0; n < NF; ++n) {
            int rr = wc * (BN / 2) + n * 16 + lr;
            bh[n] = *(u16x8*)&LBh[rr * PS + lq * 8];
            bl[n] = *(u16x8*)&LBl[rr * PS + lq * 8];
        }
        #pragma unroll
        for (int m = 0; m < MF; ++m)
            #pragma unroll
            for (int n = 0; n < NF; ++n) {
                asm("v_mfma_f32_16x16x32_bf16 %0, %1, %2, %0" : "+v"(acc[m][n]) : "v"(ah[m]), "v"(bh[n]));
                asm("v_mfma_f32_16x16x32_bf16 %0, %1, %2, %0" : "+v"(acc[m][n]) : "v"(ah[m]), "v"(bl[n]));
                asm("v_mfma_f32_16x16x32_bf16 %0, %1, %2, %0" : "+v"(acc[m][n]) : "v"(al[m]), "v"(bh[n]));
            }
    }
    #pragma unroll
    for (int m = 0; m < MF; ++m)
        #pragma unroll
        for (int n = 0; n < NF; ++n) {
            int col = bn + wc * (BN / 2) + n * 16 + lr;
            #pragma unroll
            for (int r = 0; r < 4; ++r) {
                int row = bm + wr * (BM / 2) + m * 16 + lq * 4 + r;
                C[(size_t)row * N + col] = acc[m][n][r];
            }
        }
}

// ======== fused: conv+silu -> x_proj MFMA -> dt+softplus -> scanA ========
__global__ __launch_bounds__(256) void fused_mid(
    const float* __restrict__ xz,
    const unsigned short* __restrict__ xpwh, const unsigned short* __restrict__ xpwl,
    const float* __restrict__ dtw, const float* __restrict__ dtb,
    const float* __restrict__ cw, const float* __restrict__ cb,
    const float* __restrict__ Af_g,
    float* __restrict__ xdbl, float* __restrict__ paO, float* __restrict__ hO) {
    const int ch = blockIdx.x & (NCH - 1);
    const int d  = threadIdx.x;
    const size_t r0 = (size_t)(blockIdx.x >> 9) * L_SEQ + ch * CS;
    __shared__ unsigned short aS[2][16][PSA];    // rows CS..15 zero
    __shared__ float P[4][16][49];
    __shared__ float xdblS[CS][41];

    // zero pad rows CS..15 (MFMA reads 16 rows)
    #pragma unroll
    for (int i = CS; i < 16; ++i) { aS[0][i][d] = 0; aS[1][i][d] = 0; }

    // ---- phase 0: conv + silu on the fly, split into LDS ----
    {
        const float w0 = cw[d * 4 + 0], w1 = cw[d * 4 + 1];
        const float w2 = cw[d * 4 + 2], w3 = cw[d * 4 + 3];
        const float bz = cb[d];
        float p0 = 0.f, p1 = 0.f, p2 = 0.f;
        if (ch > 0) {
            p0 = xz[(r0 - 3) * 512 + d];
            p1 = xz[(r0 - 2) * 512 + d];
            p2 = xz[(r0 - 1) * 512 + d];
        }
        #pragma unroll
        for (int i = 0; i < CS; ++i) {
            float cur = xz[(r0 + i) * 512 + d];
            float v = silu_f(fmaf(w3, cur, fmaf(w2, p2, fmaf(w1, p1, fmaf(w0, p0, bz)))));
            unsigned short h16, l16; splitf(v, h16, l16);
            aS[0][i][d] = h16; aS[1][i][d] = l16;
            p0 = p1; p1 = p2; p2 = cur;
        }
    }
    __syncthreads();

    // ---- phase 1: x_proj MFMA (M=16, CS live; N=48), waves split K ----
    const int w = threadIdx.x >> 6, l = threadIdx.x & 63;
    const int lr = l & 15, lq = l >> 4;
    {
        f32x4 acc[3];
        const f32x4 z4 = {0.f, 0.f, 0.f, 0.f};
        #pragma unroll
        for (int n = 0; n < 3; ++n) acc[n] = z4;
        #pragma unroll
        for (int ks = 0; ks < 2; ++ks) {
            const int kk = w * 64 + ks * 32 + lq * 8;
            u16x8 ah, al, bh[3], bl[3];
            ah = *(const u16x8*)&aS[0][lr][kk];
            al = *(const u16x8*)&aS[1][lr][kk];
            #pragma unroll
            for (int n = 0; n < 3; ++n) {
                const int c = n * 16 + lr;
                bh[n] = *(const u16x8*)&xpwh[c * DI + kk];
                bl[n] = *(const u16x8*)&xpwl[c * DI + kk];
            }
            #pragma unroll
            for (int n = 0; n < 3; ++n) {
                asm("v_mfma_f32_16x16x32_bf16 %0, %1, %2, %0" : "+v"(acc[n]) : "v"(ah), "v"(bh[n]));
                asm("v_mfma_f32_16x16x32_bf16 %0, %1, %2, %0" : "+v"(acc[n]) : "v"(ah), "v"(bl[n]));
                asm("v_mfma_f32_16x16x32_bf16 %0, %1, %2, %0" : "+v"(acc[n]) : "v"(al), "v"(bh[n]));
            }
        }
        #pragma unroll
        for (int n = 0; n < 3; ++n)
            #pragma unroll
            for (int r = 0; r < 4; ++r)
                P[w][lq * 4 + r][n * 16 + lr] = acc[n][r];
    }
    __syncthreads();
    // ---- phase 2: reduce 4 partials -> xdblS + global xdbl (rows < CS only) ----
    {
        const int i = threadIdx.x >> 4;        // 0..15
        const int cb0 = threadIdx.x & 15;
        if (i < CS) {
            for (int c = cb0; c < NXP; c += 16) {
                float s = P[0][i][c] + P[1][i][c] + P[2][i][c] + P[3][i][c];
                xdblS[i][c] = s;
                xdbl[(r0 + i) * NXP + c] = s;
            }
        }
    }
    __syncthreads();

    // ---- phase 3: dt + softplus + scanA (zero init), u rebuilt from aS ----
    float wt[DTR];
    #pragma unroll
    for (int r = 0; r < DTR; ++r) wt[r] = dtw[d * DTR + r];
    const float bt = dtb[d];
    float Af[DST], h[DST], pa[DST];
    #pragma unroll
    for (int n = 0; n < DST; ++n) {
        Af[n] = Af_g[d * DST + n];
        h[n] = 0.f; pa[n] = 1.f;
    }
    #pragma unroll
    for (int i = 0; i < CS; ++i) {
        float s = bt;
        #pragma unroll
        for (int r = 0; r < DTR; ++r) s = fmaf(xdblS[i][r], wt[r], s);
        const float dl = softplus_f(s);
        const float u = bf2f(aS[0][i][d]) + bf2f(aS[1][i][d]);
        const float du = dl * u;
        #pragma unroll
        for (int n = 0; n < DST; ++n) {
            const float dA = fexp2(dl * Af[n]);
            pa[n] *= dA;
            h[n] = fmaf(dA, h[n], du * xdblS[i][DTR + n]);
        }
    }
    const size_t o = ((size_t)blockIdx.x * DI + d) * DST;
    #pragma unroll
    for (int n = 0; n < DST; ++n) { paO[o + n] = pa[n]; hO[o + n] = h[n]; }
}

// ---------------- combine chunk states; paO becomes exclusive init ----------------
__global__ void scan_combine(float* __restrict__ paO, const float* __restrict__ hO) {
    const int t  = blockIdx.x * 64 + threadIdx.x;   // over B*DI*DST = 8192
    const int b  = t / (DI * DST);
    const int dn = t % (DI * DST);
    float run = 0.f;
    for (int ch0 = 0; ch0 < NCH; ch0 += 8) {
        float pav[8], hv[8];
        #pragma unroll
        for (int j = 0; j < 8; ++j) {
            size_t o = ((size_t)(b * NCH + ch0 + j)) * DI * DST + dn;
            pav[j] = paO[o]; hv[j] = hO[o];
        }
        #pragma unroll
        for (int j = 0; j < 8; ++j) {
            size_t o = ((size_t)(b * NCH + ch0 + j)) * DI * DST + dn;
            paO[o] = run;
            run = fmaf(pav[j], run, hv[j]);
        }
    }
}

// ======== fused: conv on-the-fly -> scanC + gate -> out_proj (MFMA) ========
__global__ __launch_bounds__(256) void fused_out(
    const float* __restrict__ xz, const float* __restrict__ xdbl,
    const unsigned short* __restrict__ owh, const unsigned short* __restrict__ owl,
    const float* __restrict__ dtw, const float* __restrict__ dtb,
    const float* __restrict__ cw, const float* __restrict__ cb,
    const float* __restrict__ Af_g, const float* __restrict__ D_skip,
    const float* __restrict__ hinit,
    unsigned short* __restrict__ hh, unsigned short* __restrict__ hl) {
    const int ch = blockIdx.x & (NCH - 1);
    const int d  = threadIdx.x;
    const size_t r0 = (size_t)(blockIdx.x >> 9) * L_SEQ + ch * CS;
    __shared__ unsigned short yS[2][16][PSA];    // rows CS..15 zero
    __shared__ float xdblS[CS][41];

    #pragma unroll
    for (int i = CS; i < 16; ++i) { yS[0][i][d] = 0; yS[1][i][d] = 0; }
    {
        const float* src = xdbl + r0 * NXP;
        for (int idx = threadIdx.x; idx < CS * NXP; idx += 256)
            xdblS[idx / NXP][idx % NXP] = src[idx];
    }
    float wt[DTR];
    #pragma unroll
    for (int r = 0; r < DTR; ++r) wt[r] = dtw[d * DTR + r];
    const float bt = dtb[d];
    const float Dd = D_skip[d];
    const float w0 = cw[d * 4 + 0], w1 = cw[d * 4 + 1];
    const float w2 = cw[d * 4 + 2], w3 = cw[d * 4 + 3];
    const float bz = cb[d];
    float Af[DST], h[DST];
    const size_t o = ((size_t)blockIdx.x * DI + d) * DST;
    #pragma unroll
    for (int n = 0; n < DST; ++n) {
        Af[n] = Af_g[d * DST + n];
        h[n] = hinit[o + n];
    }
    float p0 = 0.f, p1 = 0.f, p2 = 0.f;
    if (ch > 0) {
        p0 = xz[(r0 - 3) * 512 + d];
        p1 = xz[(r0 - 2) * 512 + d];
        p2 = xz[(r0 - 1) * 512 + d];
    }
    __syncthreads();

    // ---- scanC + skip + gate (conv inline), y split into LDS ----
    #pragma unroll
    for (int i = 0; i < CS; ++i) {
        const float cur = xz[(r0 + i) * 512 + d];
        const float zv  = xz[(r0 + i) * 512 + DI + d];
        const float u = silu_f(fmaf(w3, cur, fmaf(w2, p2, fmaf(w1, p1, fmaf(w0, p0, bz)))));
        p0 = p1; p1 = p2; p2 = cur;
        float s = bt;
        #pragma unroll
        for (int r = 0; r < DTR; ++r) s = fmaf(xdblS[i][r], wt[r], s);
        const float dl = softplus_f(s);
        const float du = dl * u;
        float acc = 0.f;
        #pragma unroll
        for (int n = 0; n < DST; ++n) {
            const float dA = fexp2(dl * Af[n]);
            h[n] = fmaf(dA, h[n], du * xdblS[i][DTR + n]);
            acc = fmaf(h[n], xdblS[i][DTR + DST + n], acc);
        }
        const float y = (acc + u * Dd) * silu_f(zv);
        unsigned short h16, l16; splitf(y, h16, l16);
        yS[0][i][d] = h16; yS[1][i][d] = l16;
    }
    __syncthreads();

    // ---- out_proj MFMA: M=16 rows (CS live), wave w owns cols w*32.., K=256 ----
    const int w = threadIdx.x >> 6, l = threadIdx.x & 63;
    const int lr = l & 15, lq = l >> 4;
    f32x4 acc[2];
    const f32x4 z4 = {0.f, 0.f, 0.f, 0.f};
    #pragma unroll
    for (int n = 0; n < 2; ++n) acc[n] = z4;
    #pragma unroll
    for (int ks = 0; ks < 8; ++ks) {
        const int kk = ks * 32 + lq * 8;
        u16x8 ah, al, bh[2], bl[2];
        ah = *(const u16x8*)&yS[0][lr][kk];
        al = *(const u16x8*)&yS[1][lr][kk];
        #pragma unroll
        for (int n = 0; n < 2; ++n) {
            const int c = w * 32 + n * 16 + lr;
            bh[n] = *(const u16x8*)&owh[c * DI + kk];
            bl[n] = *(const u16x8*)&owl[c * DI + kk];
        }
        #pragma unroll
        for (int n = 0; n < 2; ++n) {
            asm("v_mfma_f32_16x16x32_bf16 %0, %1, %2, %0" : "+v"(acc[n]) : "v"(ah), "v"(bh[n]));
            asm("v_mfma_f32_16x16x32_bf16 %0, %1, %2, %0" : "+v"(acc[n]) : "v"(ah), "v"(bl[n]));
            asm("v_mfma_f32_16x16x32_bf16 %0, %1, %2, %0" : "+v"(acc[n]) : "v"(al), "v"(bh[n]));
        }
    }
    if (lq < CS / 4) {
        #pragma unroll
        for (int n = 0; n < 2; ++n) {
            const int col = w * 32 + n * 16 + lr;
            #pragma unroll
            for (int r = 0; r < 4; ++r) {
                const size_t row = r0 + lq * 4 + r;
                unsigned short h16, l16; splitf(acc[n][r], h16, l16);
                hh[row * DIMC + col] = h16;
                hl[row * DIMC + col] = l16;
            }
        }
    }
}

// ---------------- RMSNorm over C=128 + transpose (B,L,C) -> (B,C,L) ----------------
__global__ void rms_out(const unsigned short* __restrict__ hh, const unsigned short* __restrict__ hl,
                        const float* __restrict__ rw, float* __restrict__ out) {
    __shared__ float tile[64][129];
    __shared__ float rinv[64];
    const int blk = blockIdx.x;
    const int b = blk / (L_SEQ / 64);
    const int l0 = (blk % (L_SEQ / 64)) * 64;
    const int t = threadIdx.x;
    for (int k = 0; k < 32; ++k) {
        int idx = k * 256 + t;
        int l = idx >> 7, cc = idx & 127;
        size_t o = ((size_t)b * L_SEQ + l0 + l) * DIMC + cc;
        tile[l][cc] = bf2f(hh[o]) + bf2f(hl[o]);
    }
    __syncthreads();
    if (t < 64) {
        float s = 0.f;
        for (int cc = 0; cc < DIMC; ++cc) { float v = tile[t][cc]; s += v * v; }
        rinv[t] = rsqrtf(s / DIMC + 1e-6f);
    }
    __syncthreads();
    for (int k = 0; k < 32; ++k) {
        int odx = k * 256 + t;
        int cc = odx >> 6, li = odx & 63;
        out[((size_t)b * DIMC + cc) * L_SEQ + l0 + li] = tile[li][cc] * rinv[li] * rw[cc];
    }
}

extern "C" void kernel_launch(void* const* d_in, const int* in_sizes, int n_in,
                              void* d_out, int out_size, void* d_ws, size_t ws_size,
                              hipStream_t stream) {
    const float* x      = (const float*)d_in[0];
    const float* in_w   = (const float*)d_in[1];
    const float* conv_w = (const float*)d_in[2];
    const float* conv_b = (const float*)d_in[3];
    const float* xp_w   = (const float*)d_in[4];
    const float* dt_w   = (const float*)d_in[5];
    const float* dt_b   = (const float*)d_in[6];
    const float* A_log  = (const float*)d_in[7];
    const float* D_skip = (const float*)d_in[8];
    const float* out_w  = (const float*)d_in[9];
    const float* rms_w  = (const float*)d_in[10];
    float* out = (float*)d_out;

    const int M = B_SZ * L_SEQ;   // 8192
    char* p = (char*)d_ws;
    auto alloc = [&](size_t bytes) -> void* {
        void* r = (void*)p; p += (bytes + 255) & ~(size_t)255; return r;
    };
    float* xz   = (float*)alloc((size_t)M * 512 * 4);
    float* xdbl = (float*)alloc((size_t)M * NXP * 4);
    float* paB  = (float*)alloc((size_t)B_SZ * NCH * DI * DST * 4);
    float* hB   = (float*)alloc((size_t)B_SZ * NCH * DI * DST * 4);
    float* AfT  = (float*)alloc((size_t)N_AF * 4);
    unsigned short* hh0 = (unsigned short*)alloc((size_t)M * DIMC * 2);
    unsigned short* hl0 = (unsigned short*)alloc((size_t)M * DIMC * 2);
    unsigned short* hh1 = (unsigned short*)alloc((size_t)M * DIMC * 2);
    unsigned short* hl1 = (unsigned short*)alloc((size_t)M * DIMC * 2);
    unsigned short* iwh = (unsigned short*)alloc((size_t)N_INW * 2);
    unsigned short* iwl = (unsigned short*)alloc((size_t)N_INW * 2);
    unsigned short* xpwh = (unsigned short*)alloc((size_t)N_XPW * 2);
    unsigned short* xpwl = (unsigned short*)alloc((size_t)N_XPW * 2);
    unsigned short* owh = (unsigned short*)alloc((size_t)N_OW * 2);
    unsigned short* owl = (unsigned short*)alloc((size_t)N_OW * 2);

    prep<<<(N_INW + 255) / 256, 256, 0, stream>>>(
        in_w, xp_w, out_w, A_log, iwh, iwl, xpwh, xpwl, owh, owl, AfT);

    transpose_in<<<dim3(B_SZ, DIMC / 32, L_SEQ / 32), dim3(32, 8), 0, stream>>>(x, hh0, hl0);

    unsigned short *hhin = hh0, *hlin = hl0, *hhout = hh1, *hlout = hl1;
    for (int layer = 0; layer < NLAYER; ++layer) {
        const float* cw  = conv_w + (size_t)layer * DI * 4;
        const float* cb  = conv_b + (size_t)layer * DI;
        const float* dtw = dt_w   + (size_t)layer * DI * DTR;
        const float* dtb = dt_b   + (size_t)layer * DI;
        const float* af  = AfT    + (size_t)layer * DI * DST;
        const float* ds  = D_skip + (size_t)layer * DI;
        const size_t iwo = (size_t)layer * 512 * 128;
        const size_t xpo = (size_t)layer * NXPP * DI;
        const size_t owo = (size_t)layer * DIMC * DI;

        // in_proj: xz = h * in_w^T   (M x 512, K=128)
        gemm_sp<64, 128><<<dim3(M / 64, 4), 256, 0, stream>>>(
            hhin, hlin, iwh + iwo, iwl + iwo, xz, M, 512, 128);
        // conv+silu -> x_proj (MFMA) -> dt -> scanA  (1024 blocks = 4/CU)
        fused_mid<<<B_SZ * NCH, 256, 0, stream>>>(
            xz, xpwh + xpo, xpwl + xpo, dtw, dtb, cw, cb, af, xdbl, paB, hB);
        scan_combine<<<(B_SZ * DI * DST) / 64, 64, 0, stream>>>(paB, hB);
        // scanC + gate -> out_proj (MFMA) -> split  (1024 blocks = 4/CU)
        fused_out<<<B_SZ * NCH, 256, 0, stream>>>(
            xz, xdbl, owh + owo, owl + owo, dtw, dtb, cw, cb, af, ds, paB,
            hhout, hlout);

        unsigned short* ts;
        ts = hhin; hhin = hhout; hhout = ts;
        ts = hlin; hlin = hlout; hlout = ts;
    }

    rms_out<<<B_SZ * (L_SEQ / 64), 256, 0, stream>>>(hhin, hlin, rms_w, out);
}

// Round 13
// 544.236 us; speedup vs baseline: 1.3214x; 1.3214x over previous
//
#include <hip/hip_runtime.h>
#include <math.h>

#define B_SZ   2
#define L_SEQ  4096
#define DIMC   128
#define DI     256      // D_INNER
#define DST    16       // D_STATE
#define DTR    8        // DT_RANK
#define NXP    40       // DTR + 2*DST
#define NXPP   48      // padded to MFMA tile
#define NLAYER 8
#define NCH    256      // chunks per batch
#define CS     16       // rows per chunk
#define LOG2E  1.4426950408889634f
#define LN2    0.6931471805599453f
#define PSA    264      // u16 LDS row stride for MFMA A tiles

#define N_INW  (NLAYER * 512 * 128)
#define N_XPW  (NLAYER * NXPP * DI)
#define N_OW   (NLAYER * DIMC * DI)
#define N_AF   (NLAYER * DI * DST)

typedef __attribute__((ext_vector_type(8))) unsigned short u16x8;
typedef __attribute__((ext_vector_type(4))) float f32x4;

__device__ __forceinline__ float fexp2(float x){ float r; asm("v_exp_f32 %0, %1" : "=v"(r) : "v"(x)); return r; }
__device__ __forceinline__ float flog2(float x){ float r; asm("v_log_f32 %0, %1" : "=v"(r) : "v"(x)); return r; }
__device__ __forceinline__ float frcp (float x){ float r; asm("v_rcp_f32 %0, %1" : "=v"(r) : "v"(x)); return r; }

__device__ __forceinline__ float silu_f(float x) {
    return x * frcp(1.f + fexp2(-x * LOG2E));
}
__device__ __forceinline__ float softplus_f(float x) {
    float t = fexp2(-fabsf(x) * LOG2E);
    return fmaxf(x, 0.f) + flog2(1.f + t) * LN2;
}
__device__ __forceinline__ void splitf(float x, unsigned short& h, unsigned short& l) {
    unsigned bx = __builtin_bit_cast(unsigned, x);
    h = (unsigned short)(bx >> 16);
    float fh = __builtin_bit_cast(float, bx & 0xffff0000u);
    float r = x - fh;
    l = (unsigned short)(__builtin_bit_cast(unsigned, r) >> 16);
}
__device__ __forceinline__ float bf2f(unsigned short u) {
    return __builtin_bit_cast(float, (unsigned)u << 16);
}

// ---------------- one prep kernel: all weight splits + Af table ----------------
__global__ void prep(const float* __restrict__ in_w, const float* __restrict__ xp_w,
                     const float* __restrict__ out_w, const float* __restrict__ A_log,
                     unsigned short* __restrict__ iwh, unsigned short* __restrict__ iwl,
                     unsigned short* __restrict__ xpwh, unsigned short* __restrict__ xpwl,
                     unsigned short* __restrict__ owh, unsigned short* __restrict__ owl,
                     float* __restrict__ Af) {
    const int i = blockIdx.x * 256 + threadIdx.x;
    if (i < N_INW) { unsigned short h, l; splitf(in_w[i], h, l); iwh[i] = h; iwl[i] = l; }
    if (i < N_XPW) {
        int ly = i / (NXPP * DI), rem = i % (NXPP * DI);
        int c = rem / DI, k = rem % DI;
        unsigned short h = 0, l = 0;
        if (c < NXP) splitf(xp_w[((size_t)ly * NXP + c) * DI + k], h, l);
        xpwh[i] = h; xpwl[i] = l;
    }
    if (i < N_OW) { unsigned short h, l; splitf(out_w[i], h, l); owh[i] = h; owl[i] = l; }
    if (i < N_AF) Af[i] = -expf(A_log[i]) * LOG2E;
}

// ---------------- transpose (B,C,L) -> (B,L,C), emit split bf16 ----------------
__global__ void transpose_in(const float* __restrict__ x, unsigned short* __restrict__ hh,
                             unsigned short* __restrict__ hl) {
    __shared__ float tl[32][33];
    const int b  = blockIdx.x;
    const int c0 = blockIdx.y * 32;
    const int l0 = blockIdx.z * 32;
    const int tx = threadIdx.x;
    const int ty = threadIdx.y;
    #pragma unroll
    for (int r = 0; r < 4; ++r) {
        int c = c0 + ty + r * 8;
        tl[ty + r * 8][tx] = x[((size_t)b * DIMC + c) * L_SEQ + l0 + tx];
    }
    __syncthreads();
    #pragma unroll
    for (int r = 0; r < 4; ++r) {
        int l = l0 + ty + r * 8;
        float v = tl[tx][ty + r * 8];
        size_t o = ((size_t)b * L_SEQ + l) * DIMC + c0 + tx;
        unsigned short h16, l16; splitf(v, h16, l16);
        hh[o] = h16; hl[o] = l16;
    }
}

// ---------------- MFMA GEMM: C[M,N] = A[M,K] * W[N,K]^T  (split-bf16, 3-pass) ----------------
template<int BM, int BN>
__global__ __launch_bounds__(256) void gemm_sp(
    const unsigned short* __restrict__ Ahg, const unsigned short* __restrict__ Alg,
    const unsigned short* __restrict__ Whg, const unsigned short* __restrict__ Wlg,
    float* __restrict__ C, int M, int N, int K) {
    constexpr int PS = 40;
    __shared__ unsigned short lds[(BM + BN) * 2 * PS];
    unsigned short* LAh = lds;
    unsigned short* LAl = LAh + BM * PS;
    unsigned short* LBh = LAl + BM * PS;
    unsigned short* LBl = LBh + BN * PS;
    const int t = threadIdx.x;
    const int w = t >> 6, l = t & 63;
    const int wr = w >> 1, wc = w & 1;
    const int lr = l & 15, lq = l >> 4;
    constexpr int MF = BM / 32, NF = BN / 32;
    const int bm = blockIdx.x * BM, bn = blockIdx.y * BN;
    f32x4 acc[MF][NF];
    const f32x4 z4 = {0.f, 0.f, 0.f, 0.f};
    #pragma unroll
    for (int m = 0; m < MF; ++m)
        #pragma unroll
        for (int n = 0; n < NF; ++n) acc[m][n] = z4;

    for (int k0 = 0; k0 < K; k0 += 32) {
        if (k0) __syncthreads();
        #pragma unroll
        for (int s = 0; s < BM * 4 / 256; ++s) {
            int task = t + s * 256;
            int r = task >> 2, g = task & 3;
            size_t go = (size_t)(bm + r) * K + k0 + g * 8;
            *(u16x8*)&LAh[r * PS + g * 8] = *(const u16x8*)&Ahg[go];
            *(u16x8*)&LAl[r * PS + g * 8] = *(const u16x8*)&Alg[go];
        }
        #pragma unroll
        for (int s = 0; s < BN * 4 / 256; ++s) {
            int task = t + s * 256;
            int r = task >> 2, g = task & 3;
            size_t go = (size_t)(bn + r) * K + k0 + g * 8;
            *(u16x8*)&LBh[r * PS + g * 8] = *(const u16x8*)&Whg[go];
            *(u16x8*)&LBl[r * PS + g * 8] = *(const u16x8*)&Wlg[go];
        }
        __syncthreads();
        u16x8 ah[MF], al[MF], bh[NF], bl[NF];
        #pragma unroll
        for (int m = 0; m < MF; ++m) {
            int rr = wr * (BM / 2) + m * 16 + lr;
            ah[m] = *(u16x8*)&LAh[rr * PS + lq * 8];
            al[m] = *(u16x8*)&LAl[rr * PS + lq * 8];
        }
        #pragma unroll
        for (int n = 0; n < NF; ++n) {
            int rr = wc * (BN / 2) + n * 16 + lr;
            bh[n] = *(u16x8*)&LBh[rr * PS + lq * 8];
            bl[n] = *(u16x8*)&LBl[rr * PS + lq * 8];
        }
        #pragma unroll
        for (int m = 0; m < MF; ++m)
            #pragma unroll
            for (int n = 0; n < NF; ++n) {
                asm("v_mfma_f32_16x16x32_bf16 %0, %1, %2, %0" : "+v"(acc[m][n]) : "v"(ah[m]), "v"(bh[n]));
                asm("v_mfma_f32_16x16x32_bf16 %0, %1, %2, %0" : "+v"(acc[m][n]) : "v"(ah[m]), "v"(bl[n]));
                asm("v_mfma_f32_16x16x32_bf16 %0, %1, %2, %0" : "+v"(acc[m][n]) : "v"(al[m]), "v"(bh[n]));
            }
    }
    #pragma unroll
    for (int m = 0; m < MF; ++m)
        #pragma unroll
        for (int n = 0; n < NF; ++n) {
            int col = bn + wc * (BN / 2) + n * 16 + lr;
            #pragma unroll
            for (int r = 0; r < 4; ++r) {
                int row = bm + wr * (BM / 2) + m * 16 + lq * 4 + r;
                C[(size_t)row * N + col] = acc[m][n][r];
            }
        }
}

// ======== fused: conv+silu -> x_proj MFMA -> dt+softplus -> scanA ========
__global__ __launch_bounds__(256) void fused_mid(
    const float* __restrict__ xz,
    const unsigned short* __restrict__ xpwh, const unsigned short* __restrict__ xpwl,
    const float* __restrict__ dtw, const float* __restrict__ dtb,
    const float* __restrict__ cw, const float* __restrict__ cb,
    const float* __restrict__ Af_g,
    float* __restrict__ xdbl, float* __restrict__ paO, float* __restrict__ hO) {
    const int ch = blockIdx.x & (NCH - 1);
    const int d  = threadIdx.x;
    const size_t r0 = (size_t)(blockIdx.x >> 8) * L_SEQ + ch * CS;
    __shared__ unsigned short aS[2][CS][PSA];
    __shared__ float P[4][CS][49];
    __shared__ float xdblS[CS][41];

    {
        const float w0 = cw[d * 4 + 0], w1 = cw[d * 4 + 1];
        const float w2 = cw[d * 4 + 2], w3 = cw[d * 4 + 3];
        const float bz = cb[d];
        float p0 = 0.f, p1 = 0.f, p2 = 0.f;
        if (ch > 0) {
            p0 = xz[(r0 - 3) * 512 + d];
            p1 = xz[(r0 - 2) * 512 + d];
            p2 = xz[(r0 - 1) * 512 + d];
        }
        #pragma unroll 4
        for (int i = 0; i < CS; ++i) {
            float cur = xz[(r0 + i) * 512 + d];
            float v = silu_f(fmaf(w3, cur, fmaf(w2, p2, fmaf(w1, p1, fmaf(w0, p0, bz)))));
            unsigned short h16, l16; splitf(v, h16, l16);
            aS[0][i][d] = h16; aS[1][i][d] = l16;
            p0 = p1; p1 = p2; p2 = cur;
        }
    }
    __syncthreads();

    const int w = threadIdx.x >> 6, l = threadIdx.x & 63;
    const int lr = l & 15, lq = l >> 4;
    {
        f32x4 acc[3];
        const f32x4 z4 = {0.f, 0.f, 0.f, 0.f};
        #pragma unroll
        for (int n = 0; n < 3; ++n) acc[n] = z4;
        #pragma unroll
        for (int ks = 0; ks < 2; ++ks) {
            const int kk = w * 64 + ks * 32 + lq * 8;
            u16x8 ah, al, bh[3], bl[3];
            ah = *(const u16x8*)&aS[0][lr][kk];
            al = *(const u16x8*)&aS[1][lr][kk];
            #pragma unroll
            for (int n = 0; n < 3; ++n) {
                const int c = n * 16 + lr;
                bh[n] = *(const u16x8*)&xpwh[c * DI + kk];
                bl[n] = *(const u16x8*)&xpwl[c * DI + kk];
            }
            #pragma unroll
            for (int n = 0; n < 3; ++n) {
                asm("v_mfma_f32_16x16x32_bf16 %0, %1, %2, %0" : "+v"(acc[n]) : "v"(ah), "v"(bh[n]));
                asm("v_mfma_f32_16x16x32_bf16 %0, %1, %2, %0" : "+v"(acc[n]) : "v"(ah), "v"(bl[n]));
                asm("v_mfma_f32_16x16x32_bf16 %0, %1, %2, %0" : "+v"(acc[n]) : "v"(al), "v"(bh[n]));
            }
        }
        #pragma unroll
        for (int n = 0; n < 3; ++n)
            #pragma unroll
            for (int r = 0; r < 4; ++r)
                P[w][lq * 4 + r][n * 16 + lr] = acc[n][r];
    }
    __syncthreads();
    {
        const int i = threadIdx.x >> 4;
        const int cb0 = threadIdx.x & 15;
        for (int c = cb0; c < NXP; c += 16) {
            float s = P[0][i][c] + P[1][i][c] + P[2][i][c] + P[3][i][c];
            xdblS[i][c] = s;
            xdbl[(r0 + i) * NXP + c] = s;
        }
    }
    __syncthreads();

    float wt[DTR];
    #pragma unroll
    for (int r = 0; r < DTR; ++r) wt[r] = dtw[d * DTR + r];
    const float bt = dtb[d];
    float Af[DST], h[DST], pa[DST];
    #pragma unroll
    for (int n = 0; n < DST; ++n) {
        Af[n] = Af_g[d * DST + n];
        h[n] = 0.f; pa[n] = 1.f;
    }
    #pragma unroll 4
    for (int i = 0; i < CS; ++i) {
        float s = bt;
        #pragma unroll
        for (int r = 0; r < DTR; ++r) s = fmaf(xdblS[i][r], wt[r], s);
        const float dl = softplus_f(s);
        const float u = bf2f(aS[0][i][d]) + bf2f(aS[1][i][d]);
        const float du = dl * u;
        #pragma unroll
        for (int n = 0; n < DST; ++n) {
            const float dA = fexp2(dl * Af[n]);
            pa[n] *= dA;
            h[n] = fmaf(dA, h[n], du * xdblS[i][DTR + n]);
        }
    }
    const size_t o = ((size_t)blockIdx.x * DI + d) * DST;
    #pragma unroll
    for (int n = 0; n < DST; ++n) { paO[o + n] = pa[n]; hO[o + n] = h[n]; }
}

// ---------------- combine chunk states; paO becomes exclusive init ----------------
__global__ void scan_combine(float* __restrict__ paO, const float* __restrict__ hO) {
    const int t  = blockIdx.x * 64 + threadIdx.x;   // over B*DI*DST = 8192
    const int b  = t / (DI * DST);
    const int dn = t % (DI * DST);
    float run = 0.f;
    for (int ch0 = 0; ch0 < NCH; ch0 += 8) {
        float pav[8], hv[8];
        #pragma unroll
        for (int j = 0; j < 8; ++j) {
            size_t o = ((size_t)(b * NCH + ch0 + j)) * DI * DST + dn;
            pav[j] = paO[o]; hv[j] = hO[o];
        }
        #pragma unroll
        for (int j = 0; j < 8; ++j) {
            size_t o = ((size_t)(b * NCH + ch0 + j)) * DI * DST + dn;
            paO[o] = run;
            run = fmaf(pav[j], run, hv[j]);
        }
    }
}

// ======== fused: conv -> scanC + gate -> out_proj (MFMA) [+ RMS epilogue if LAST] ========
template<int LAST>
__global__ __launch_bounds__(256) void fused_out(
    const float* __restrict__ xz, const float* __restrict__ xdbl,
    const unsigned short* __restrict__ owh, const unsigned short* __restrict__ owl,
    const float* __restrict__ dtw, const float* __restrict__ dtb,
    const float* __restrict__ cw, const float* __restrict__ cb,
    const float* __restrict__ Af_g, const float* __restrict__ D_skip,
    const float* __restrict__ hinit,
    unsigned short* __restrict__ hh, unsigned short* __restrict__ hl,
    const float* __restrict__ rw, float* __restrict__ out) {
    __shared__ __align__(16) char smem[19520];
    unsigned short* ySh = (unsigned short*)smem;            // [16][264] (8448 B)
    unsigned short* ySl = ySh + CS * PSA;                   // [16][264] (8448 B)
    float (*xdblS)[41] = (float (*)[41])(smem + 16896);     // [16][41]  (2624 B)
    const int ch = blockIdx.x & (NCH - 1);
    const int d  = threadIdx.x;
    const int b  = blockIdx.x >> 8;
    const size_t r0 = (size_t)b * L_SEQ + ch * CS;

    {
        const float* src = xdbl + r0 * NXP;
        for (int idx = threadIdx.x; idx < CS * NXP; idx += 256)
            xdblS[idx / NXP][idx % NXP] = src[idx];
    }
    float wt[DTR];
    #pragma unroll
    for (int r = 0; r < DTR; ++r) wt[r] = dtw[d * DTR + r];
    const float bt = dtb[d];
    const float Dd = D_skip[d];
    const float w0 = cw[d * 4 + 0], w1 = cw[d * 4 + 1];
    const float w2 = cw[d * 4 + 2], w3 = cw[d * 4 + 3];
    const float bz = cb[d];
    float Af[DST], h[DST];
    const size_t o = ((size_t)blockIdx.x * DI + d) * DST;
    #pragma unroll
    for (int n = 0; n < DST; ++n) {
        Af[n] = Af_g[d * DST + n];
        h[n] = hinit[o + n];
    }
    float p0 = 0.f, p1 = 0.f, p2 = 0.f;
    if (ch > 0) {
        p0 = xz[(r0 - 3) * 512 + d];
        p1 = xz[(r0 - 2) * 512 + d];
        p2 = xz[(r0 - 1) * 512 + d];
    }
    __syncthreads();

    // ---- scanC + skip + gate (conv inline), y split into LDS ----
    #pragma unroll 4
    for (int i = 0; i < CS; ++i) {
        const float cur = xz[(r0 + i) * 512 + d];
        const float zv  = xz[(r0 + i) * 512 + DI + d];
        const float u = silu_f(fmaf(w3, cur, fmaf(w2, p2, fmaf(w1, p1, fmaf(w0, p0, bz)))));
        p0 = p1; p1 = p2; p2 = cur;
        float s = bt;
        #pragma unroll
        for (int r = 0; r < DTR; ++r) s = fmaf(xdblS[i][r], wt[r], s);
        const float dl = softplus_f(s);
        const float du = dl * u;
        float acc = 0.f;
        #pragma unroll
        for (int n = 0; n < DST; ++n) {
            const float dA = fexp2(dl * Af[n]);
            h[n] = fmaf(dA, h[n], du * xdblS[i][DTR + n]);
            acc = fmaf(h[n], xdblS[i][DTR + DST + n], acc);
        }
        const float y = (acc + u * Dd) * silu_f(zv);
        unsigned short h16, l16; splitf(y, h16, l16);
        ySh[i * PSA + d] = h16; ySl[i * PSA + d] = l16;
    }
    __syncthreads();

    // ---- out_proj MFMA: M=16 rows, wave w owns cols w*32..w*32+31, K=256 ----
    const int w = threadIdx.x >> 6, l = threadIdx.x & 63;
    const int lr = l & 15, lq = l >> 4;
    f32x4 acc[2];
    const f32x4 z4 = {0.f, 0.f, 0.f, 0.f};
    #pragma unroll
    for (int n = 0; n < 2; ++n) acc[n] = z4;
    #pragma unroll
    for (int ks = 0; ks < 8; ++ks) {
        const int kk = ks * 32 + lq * 8;
        u16x8 ah = *(const u16x8*)&ySh[lr * PSA + kk];
        u16x8 al = *(const u16x8*)&ySl[lr * PSA + kk];
        #pragma unroll
        for (int n = 0; n < 2; ++n) {
            const int c = w * 32 + n * 16 + lr;
            u16x8 bh = *(const u16x8*)&owh[c * DI + kk];
            u16x8 bl = *(const u16x8*)&owl[c * DI + kk];
            asm("v_mfma_f32_16x16x32_bf16 %0, %1, %2, %0" : "+v"(acc[n]) : "v"(ah), "v"(bh));
            asm("v_mfma_f32_16x16x32_bf16 %0, %1, %2, %0" : "+v"(acc[n]) : "v"(ah), "v"(bl));
            asm("v_mfma_f32_16x16x32_bf16 %0, %1, %2, %0" : "+v"(acc[n]) : "v"(al), "v"(bh));
        }
    }

    if constexpr (!LAST) {
        // split h' -> global for next layer's in_proj GEMM
        #pragma unroll
        for (int n = 0; n < 2; ++n) {
            const int col = w * 32 + n * 16 + lr;
            #pragma unroll
            for (int r = 0; r < 4; ++r) {
                const size_t row = r0 + lq * 4 + r;
                unsigned short h16, l16; splitf(acc[n][r], h16, l16);
                hh[row * DIMC + col] = h16;
                hl[row * DIMC + col] = l16;
            }
        }
    } else {
        // ---- RMS epilogue: h' rows are block-local (16 rows x 128 cols) ----
        __syncthreads();                        // yS dead after MFMA reads
        float (*hS)[132] = (float (*)[132])smem;   // 16*132*4 = 8448 B (in yS region)
        float* ps   = (float*)(smem + 8448);       // [16][16] partials (1024 B)
        float* rinv = (float*)(smem + 8448 + 1024);// [16]
        #pragma unroll
        for (int n = 0; n < 2; ++n) {
            const int col = w * 32 + n * 16 + lr;
            #pragma unroll
            for (int r = 0; r < 4; ++r)
                hS[lq * 4 + r][col] = acc[n][r];
        }
        __syncthreads();
        {
            const int row = threadIdx.x >> 4, seg = threadIdx.x & 15;
            float s = 0.f;
            #pragma unroll
            for (int j = 0; j < 8; ++j) { float v = hS[row][seg * 8 + j]; s = fmaf(v, v, s); }
            ps[row * 16 + seg] = s;
        }
        __syncthreads();
        if (threadIdx.x < 16) {
            float s = 0.f;
            #pragma unroll
            for (int k = 0; k < 16; ++k) s += ps[threadIdx.x * 16 + k];
            rinv[threadIdx.x] = rsqrtf(s / DIMC + 1e-6f);
        }
        __syncthreads();
        {
            // thread t: cc = t>>1, rows half*8..half*8+7 ; out[(b*128+cc)*4096 + ch*16 + row]
            const int cc = threadIdx.x >> 1, half = threadIdx.x & 1;
            const float rwc = rw[cc];
            float v[8];
            #pragma unroll
            for (int j = 0; j < 8; ++j) {
                const int row = half * 8 + j;
                v[j] = hS[row][cc] * rinv[row] * rwc;
            }
            float* dst = out + ((size_t)b * DIMC + cc) * L_SEQ + ch * CS + half * 8;
            *(f32x4*)dst       = *(f32x4*)&v[0];
            *(f32x4*)(dst + 4) = *(f32x4*)&v[4];
        }
    }
}

extern "C" void kernel_launch(void* const* d_in, const int* in_sizes, int n_in,
                              void* d_out, int out_size, void* d_ws, size_t ws_size,
                              hipStream_t stream) {
    const float* x      = (const float*)d_in[0];
    const float* in_w   = (const float*)d_in[1];
    const float* conv_w = (const float*)d_in[2];
    const float* conv_b = (const float*)d_in[3];
    const float* xp_w   = (const float*)d_in[4];
    const float* dt_w   = (const float*)d_in[5];
    const float* dt_b   = (const float*)d_in[6];
    const float* A_log  = (const float*)d_in[7];
    const float* D_skip = (const float*)d_in[8];
    const float* out_w  = (const float*)d_in[9];
    const float* rms_w  = (const float*)d_in[10];
    float* out = (float*)d_out;

    const int M = B_SZ * L_SEQ;   // 8192
    char* p = (char*)d_ws;
    auto alloc = [&](size_t bytes) -> void* {
        void* r = (void*)p; p += (bytes + 255) & ~(size_t)255; return r;
    };
    float* xz   = (float*)alloc((size_t)M * 512 * 4);
    float* xdbl = (float*)alloc((size_t)M * NXP * 4);
    float* paB  = (float*)alloc((size_t)B_SZ * NCH * DI * DST * 4);
    float* hB   = (float*)alloc((size_t)B_SZ * NCH * DI * DST * 4);
    float* AfT  = (float*)alloc((size_t)N_AF * 4);
    unsigned short* hh0 = (unsigned short*)alloc((size_t)M * DIMC * 2);
    unsigned short* hl0 = (unsigned short*)alloc((size_t)M * DIMC * 2);
    unsigned short* hh1 = (unsigned short*)alloc((size_t)M * DIMC * 2);
    unsigned short* hl1 = (unsigned short*)alloc((size_t)M * DIMC * 2);
    unsigned short* iwh = (unsigned short*)alloc((size_t)N_INW * 2);
    unsigned short* iwl = (unsigned short*)alloc((size_t)N_INW * 2);
    unsigned short* xpwh = (unsigned short*)alloc((size_t)N_XPW * 2);
    unsigned short* xpwl = (unsigned short*)alloc((size_t)N_XPW * 2);
    unsigned short* owh = (unsigned short*)alloc((size_t)N_OW * 2);
    unsigned short* owl = (unsigned short*)alloc((size_t)N_OW * 2);

    prep<<<(N_INW + 255) / 256, 256, 0, stream>>>(
        in_w, xp_w, out_w, A_log, iwh, iwl, xpwh, xpwl, owh, owl, AfT);

    transpose_in<<<dim3(B_SZ, DIMC / 32, L_SEQ / 32), dim3(32, 8), 0, stream>>>(x, hh0, hl0);

    unsigned short *hhin = hh0, *hlin = hl0, *hhout = hh1, *hlout = hl1;
    for (int layer = 0; layer < NLAYER; ++layer) {
        const float* cw  = conv_w + (size_t)layer * DI * 4;
        const float* cb  = conv_b + (size_t)layer * DI;
        const float* dtw = dt_w   + (size_t)layer * DI * DTR;
        const float* dtb = dt_b   + (size_t)layer * DI;
        const float* af  = AfT    + (size_t)layer * DI * DST;
        const float* ds  = D_skip + (size_t)layer * DI;
        const size_t iwo = (size_t)layer * 512 * 128;
        const size_t xpo = (size_t)layer * NXPP * DI;
        const size_t owo = (size_t)layer * DIMC * DI;

        // in_proj: xz = h * in_w^T   (M x 512, K=128)
        gemm_sp<64, 128><<<dim3(M / 64, 4), 256, 0, stream>>>(
            hhin, hlin, iwh + iwo, iwl + iwo, xz, M, 512, 128);
        // conv+silu -> x_proj (MFMA) -> dt -> scanA
        fused_mid<<<B_SZ * NCH, 256, 0, stream>>>(
            xz, xpwh + xpo, xpwl + xpo, dtw, dtb, cw, cb, af, xdbl, paB, hB);
        scan_combine<<<(B_SZ * DI * DST) / 64, 64, 0, stream>>>(paB, hB);
        // scanC + gate -> out_proj (MFMA); last layer fuses RMS+transpose out
        if (layer < NLAYER - 1) {
            fused_out<0><<<B_SZ * NCH, 256, 0, stream>>>(
                xz, xdbl, owh + owo, owl + owo, dtw, dtb, cw, cb, af, ds, paB,
                hhout, hlout, nullptr, nullptr);
        } else {
            fused_out<1><<<B_SZ * NCH, 256, 0, stream>>>(
                xz, xdbl, owh + owo, owl + owo, dtw, dtb, cw, cb, af, ds, paB,
                nullptr, nullptr, rms_w, out);
        }

        unsigned short* ts;
        ts = hhin; hhin = hhout; hhout = ts;
        ts = hlin; hlin = hlout; hlout = ts;
    }
}